// Round 9
// baseline (198.311 us; speedup 1.0000x reference)
//
#include <hip/hip_runtime.h>
#include <hip/hip_bf16.h>

typedef _Float16 half8 __attribute__((ext_vector_type(8)));
typedef __fp16 fp16x2 __attribute__((ext_vector_type(2)));
typedef float f32x4 __attribute__((ext_vector_type(4)));

#define B_ 8
#define U_ 1024
#define N_ 2048
#define DIN 128
#define H_ 4
#define HD 32
#define S_ 3072
#define LOG2E 1.44269504f

// ---------------- phase 1: projections + e-vectors + tiled f16 V ----------------
// (byte-identical to round 8 — this round is a timing-attribution probe)
__global__ __launch_bounds__(256) void p1_kernel(
    const float* __restrict__ uf, const float* __restrict__ nf,
    const float* __restrict__ Wu, const float* __restrict__ Wn,
    const float* __restrict__ a_un, const float* __restrict__ a_nu,
    _Float16* __restrict__ vtA, _Float16* __restrict__ vtB,
    float* __restrict__ eRowA, float* __restrict__ eColA,
    float* __restrict__ eRowB, float* __restrict__ eColB)
{
  __shared__ float fs[64][132];    // feature tile, padded
  __shared__ float WsT[32][132];   // W transposed [k][d], padded
  __shared__ float qt[32][65];     // q tile transposed [k][u]
  __shared__ float aAs[32], aBs[32];

  const int bid = blockIdx.x;
  const int tid = threadIdx.x;

  int b, rt, R;
  const float *feat, *W;
  _Float16* vt;
  float *eA, *eB;
  int aAoff, aBoff;
  const float *avA, *avB;
  if (bid < 128) {                       // users
    b = bid >> 4; rt = bid & 15; R = U_;
    feat = uf; W = Wu; vt = vtB;
    eA = eRowA; eB = eColB;
    avA = a_un; aAoff = 0;  avB = a_nu; aBoff = HD;
  } else {                               // news
    int t2 = bid - 128;
    b = t2 >> 5; rt = t2 & 31; R = N_;
    feat = nf; W = Wn; vt = vtA;
    eA = eColA; eB = eRowB;
    avA = a_un; aAoff = HD; avB = a_nu; aBoff = 0;
  }
  const int r0 = rt * 64;
  const float4* feat4 = (const float4*)(feat + ((size_t)b * R + r0) * DIN);
  #pragma unroll
  for (int i = 0; i < 8; ++i) {
    int f4 = tid + 256 * i;              // 0..2047 float4s of the 64x128 tile
    int row = f4 >> 5, c4 = f4 & 31;
    *(float4*)&fs[row][c4 * 4] = feat4[row * 32 + c4];
  }

  const int kk = tid & 15, uu = tid >> 4;    // compute mapping: 2 k-cols x 4 u-rows
  const int u2 = tid & 63, part = tid >> 6;  // store/e mapping
  float eAv[H_], eBv[H_];

  #pragma unroll
  for (int h = 0; h < H_; ++h) {
    __syncthreads();
    {
      const float4* W4 = (const float4*)(W + (size_t)h * DIN * HD);
      #pragma unroll
      for (int i = 0; i < 4; ++i) {
        int f4 = tid + 256 * i;          // 0..1023
        int d = f4 >> 3, kc = f4 & 7;
        float4 v = W4[f4];
        WsT[kc * 4 + 0][d] = v.x;
        WsT[kc * 4 + 1][d] = v.y;
        WsT[kc * 4 + 2][d] = v.z;
        WsT[kc * 4 + 3][d] = v.w;
      }
      if (tid < 32) {
        aAs[tid] = avA[h * 64 + aAoff + tid];
        aBs[tid] = avB[h * 64 + aBoff + tid];
      }
    }
    __syncthreads();
    {
      float acc0[4] = {0.f, 0.f, 0.f, 0.f}, acc1[4] = {0.f, 0.f, 0.f, 0.f};
      #pragma unroll 8
      for (int d = 0; d < DIN; d += 4) {
        float4 w0 = *(const float4*)&WsT[kk][d];
        float4 w1 = *(const float4*)&WsT[kk + 16][d];
        #pragma unroll
        for (int i = 0; i < 4; ++i) {
          float4 fv = *(const float4*)&fs[uu + 16 * i][d];
          acc0[i] = fmaf(fv.x, w0.x, acc0[i]); acc0[i] = fmaf(fv.y, w0.y, acc0[i]);
          acc0[i] = fmaf(fv.z, w0.z, acc0[i]); acc0[i] = fmaf(fv.w, w0.w, acc0[i]);
          acc1[i] = fmaf(fv.x, w1.x, acc1[i]); acc1[i] = fmaf(fv.y, w1.y, acc1[i]);
          acc1[i] = fmaf(fv.z, w1.z, acc1[i]); acc1[i] = fmaf(fv.w, w1.w, acc1[i]);
        }
      }
      #pragma unroll
      for (int i = 0; i < 4; ++i) {
        qt[kk][uu + 16 * i] = acc0[i];
        qt[kk + 16][uu + 16 * i] = acc1[i];
      }
    }
    __syncthreads();
    {
      // vt store: c = r0+u2 -> tile (r0+u2)>>5, kk=(r0+u2)&31; element [tile][krow][kk]
      size_t vtbase = (size_t)(b * H_ + h) * (R * HD)
                    + (size_t)((r0 >> 5) + (u2 >> 5)) * (HD * 32) + (u2 & 31);
      #pragma unroll
      for (int jj = 0; jj < 8; ++jj) {
        int krow = part * 8 + jj;
        vt[vtbase + krow * 32] = (_Float16)qt[krow][u2];
      }
      float a_ = 0.f, b2_ = 0.f;
      #pragma unroll
      for (int k2 = 0; k2 < HD; ++k2) {
        float qv = qt[k2][u2];
        a_  = fmaf(qv, aAs[k2], a_);
        b2_ = fmaf(qv, aBs[k2], b2_);
      }
      eAv[h] = a_  * LOG2E;   // pre-scale by log2(e): exp(x) == exp2(x*LOG2E)
      eBv[h] = b2_ * LOG2E;
    }
  }
  if (part == 0) {
    #pragma unroll
    for (int h = 0; h < H_; ++h)
      eA[(size_t)(b * H_ + h) * R + r0 + u2] = eAv[h];
  } else if (part == 1) {
    #pragma unroll
    for (int h = 0; h < H_; ++h)
      eB[(size_t)(b * H_ + h) * R + r0 + u2] = eBv[h];
  }
}

// ---------------- phase 2 core (byte-identical to round 8) ----------------
template<int RR, int CC, int ROFF, int COFF, int PAD64>
__device__ __forceinline__ void p2_core(
    int b, int rt, int wave, int l,
    const int* __restrict__ adj, const _Float16* __restrict__ vt,
    const float* __restrict__ eRow, const float* __restrict__ eCol,
    const float* __restrict__ bias, float* __restrict__ out,
    unsigned long long* maskU)
{
  constexpr int CW64 = CC / 64;          // u64 words per mask row

  // ---- stage 16 x CC adjacency strip as bits (read once, coalesced) ----
  const int* adjBase = adj + (size_t)b * S_ * S_ + (size_t)(ROFF + rt * 16) * S_ + COFF;
  #pragma unroll 4
  for (int i = 0; i < (16 * CW64) / 4; ++i) {
    int f = i * 4 + wave;
    int row = f / CW64, chunk = f % CW64;
    int av = adjBase[(size_t)row * S_ + chunk * 64 + l];
    unsigned long long m = __ballot(av != 0);
    if (l == 0) maskU[row * PAD64 + chunk] = m;
  }
  __syncthreads();

  const int h = wave;
  const int row16 = l & 15;
  const int cg = (l >> 4) << 3;          // per-lane-group K offset within 32-col tile
  const int r = rt * 16 + row16;
  const float eq = eRow[(size_t)(b * H_ + h) * RR + r];
  const float* ecolH = eCol + (size_t)(b * H_ + h) * CC;
  const _Float16* vtb = vt + (size_t)(b * H_ + h) * (CC * HD);
  const unsigned int* maskW = (const unsigned int*)maskU;
  const int mrow = row16 * (PAD64 * 2);  // u32 words per row (padded)

  f32x4 acc0 = {0.f, 0.f, 0.f, 0.f}, acc1 = {0.f, 0.f, 0.f, 0.f}, accd = {0.f, 0.f, 0.f, 0.f};
  half8 ones = {(_Float16)1.f, (_Float16)1.f, (_Float16)1.f, (_Float16)1.f,
                (_Float16)1.f, (_Float16)1.f, (_Float16)1.f, (_Float16)1.f};

  #pragma unroll 2
  for (int t = 0; t < CC / 32; ++t) {
    const int cb = t * 32 + cg;
    unsigned int mb = maskW[mrow + t] >> cg;     // same-word broadcast across groups
    float4 e0 = *(const float4*)(ecolH + cb);
    float4 e1 = *(const float4*)(ecolH + cb + 4);
    float ecv[8] = {e0.x, e0.y, e0.z, e0.w, e1.x, e1.y, e1.z, e1.w};
    float wv[8];
    #pragma unroll
    for (int j = 0; j < 8; ++j) {
      float s  = eq + ecv[j];                 // already log2e-scaled
      float ls = fmaxf(s, 0.2f * s);          // leaky (positive scale commutes)
      ls = (mb & (1u << j)) ? ls : -1e9f;     // masked -> exp2 underflows to exact 0
      wv[j] = exp2f(ls);
    }
    union { fp16x2 h2[4]; half8 h8; } uw;
    #pragma unroll
    for (int j = 0; j < 4; ++j)
      uw.h2[j] = __builtin_amdgcn_cvt_pkrtz(wv[2 * j], wv[2 * j + 1]);
    half8 w = uw.h8;
    // tile-interleaved V: [t][hd][kk] -> wave reads 2x1KB contiguous
    const half8 b0 = *(const half8*)(vtb + t * (HD * 32) + row16 * 32 + cg);
    const half8 b1 = *(const half8*)(vtb + t * (HD * 32) + (row16 + 16) * 32 + cg);
    acc0 = __builtin_amdgcn_mfma_f32_16x16x32_f16(w, b0, acc0, 0, 0, 0);
    acc1 = __builtin_amdgcn_mfma_f32_16x16x32_f16(w, b1, acc1, 0, 0, 0);
    accd = __builtin_amdgcn_mfma_f32_16x16x32_f16(w, ones, accd, 0, 0, 0);
  }

  // ---- fused epilogue: divide, bias, relu, store ----
  const int colk = row16;
  const int rowbase = rt * 16 + ((l >> 4) << 2);
  #pragma unroll
  for (int q = 0; q < 4; ++q) {
    int orow = rowbase + q;                  // C layout: col=l&15, row=(l>>4)*4+q
    size_t o = ((size_t)(b * H_ + h) * RR + orow) * 32 + colk;
    float den = accd[q];                     // den[row] replicated across cols
    float v0 = acc0[q] / den + bias[q * 32 + colk];
    float v1 = acc1[q] / den + bias[q * 32 + colk + 16];
    out[o]      = v0 > 0.f ? v0 : 0.f;
    out[o + 16] = v1 > 0.f ? v1 : 0.f;
  }
}

__global__ __launch_bounds__(256, 4) void p2_kernel(
    const int* __restrict__ adj,
    const _Float16* __restrict__ vtA, const _Float16* __restrict__ vtB,
    const float* __restrict__ eRowA, const float* __restrict__ eColA,
    const float* __restrict__ eRowB, const float* __restrict__ eColB,
    const float* __restrict__ bu, const float* __restrict__ bn,
    float* __restrict__ out)
{
  __shared__ unsigned long long maskU[16 * 33];   // max of the two instantiations
  const int tid = threadIdx.x;
  const int wave = tid >> 6, l = tid & 63;
  const int bid = blockIdx.x;
  if (bid < B_ * (U_ / 16)) {
    const int b = bid & 7, rt = bid >> 3;         // rt 0..63
    p2_core<U_, N_, 0, U_, 33>(b, rt, wave, l, adj, vtA, eRowA, eColA, bu,
                               out, maskU);
  } else {
    const int t2 = bid - B_ * (U_ / 16);
    const int b = t2 & 7, rt = t2 >> 3;           // rt 0..127
    p2_core<N_, U_, U_, 0, 17>(b, rt, wave, l, adj, vtB, eRowB, eColB, bn,
                               out + (size_t)B_ * U_ * 128, maskU);
  }
}

extern "C" void kernel_launch(void* const* d_in, const int* in_sizes, int n_in,
                              void* d_out, int out_size, void* d_ws, size_t ws_size,
                              hipStream_t stream) {
  const float* uf  = (const float*)d_in[0];
  const float* nf  = (const float*)d_in[1];
  const int*   adj = (const int*)d_in[2];
  const float* Wu  = (const float*)d_in[3];
  const float* Wn  = (const float*)d_in[4];
  const float* aun = (const float*)d_in[5];
  const float* anu = (const float*)d_in[6];
  const float* bu  = (const float*)d_in[7];
  const float* bn  = (const float*)d_in[8];

  char* ws = (char*)d_ws;
  size_t off = 0;
  _Float16* vtA = (_Float16*)(ws + off); off += (size_t)B_ * H_ * HD * N_ * 2;  // 4 MB
  _Float16* vtB = (_Float16*)(ws + off); off += (size_t)B_ * H_ * HD * U_ * 2;  // 2 MB
  float* eRowA = (float*)(ws + off); off += (size_t)B_ * H_ * U_ * 4;
  float* eColA = (float*)(ws + off); off += (size_t)B_ * H_ * N_ * 4;
  float* eRowB = (float*)(ws + off); off += (size_t)B_ * H_ * N_ * 4;
  float* eColB = (float*)(ws + off); off += (size_t)B_ * H_ * U_ * 4;
  (void)off; (void)ws_size; (void)in_sizes; (void)n_in; (void)out_size;        // ~7.7 MB total

  p1_kernel<<<384, 256, 0, stream>>>(uf, nf, Wu, Wn, aun, anu,
                                     vtA, vtB, eRowA, eColA, eRowB, eColB);
  // TIMING PROBE: p2 launched TWICE (identical writes, deterministic).
  // Round-8 total = p1 + p2 = 119.3us; this round = p1 + 2*p2.
  // => p2 = T9 - 119.3, p1 = 238.6 - T9.
  p2_kernel<<<B_ * (U_ / 16) + B_ * (N_ / 16), 256, 0, stream>>>(
      adj, vtA, vtB, eRowA, eColA, eRowB, eColB, bu, bn, (float*)d_out);
  p2_kernel<<<B_ * (U_ / 16) + B_ * (N_ / 16), 256, 0, stream>>>(
      adj, vtA, vtB, eRowA, eColA, eRowB, eColB, bu, bn, (float*)d_out);
}

// Round 10
// 159.760 us; speedup vs baseline: 1.2413x; 1.2413x over previous
//
#include <hip/hip_runtime.h>
#include <hip/hip_bf16.h>

typedef _Float16 half8 __attribute__((ext_vector_type(8)));
typedef __fp16 fp16x2 __attribute__((ext_vector_type(2)));
typedef float f32x4 __attribute__((ext_vector_type(4)));

#define B_ 8
#define U_ 1024
#define N_ 2048
#define DIN 128
#define H_ 4
#define HD 32
#define S_ 3072
#define LOG2E 1.44269504f

// ---------------- phase 1: projections + e-vectors + tiled f16 V ----------------
// HEAD-PARALLEL: one block = one (64-row tile, head). Grid 1536 (was 384 with a
// serial 4-head loop -> 8 sync phases). Adjacent bids = same tile, different head.
__global__ __launch_bounds__(256) void p1_kernel(
    const float* __restrict__ uf, const float* __restrict__ nf,
    const float* __restrict__ Wu, const float* __restrict__ Wn,
    const float* __restrict__ a_un, const float* __restrict__ a_nu,
    _Float16* __restrict__ vtA, _Float16* __restrict__ vtB,
    float* __restrict__ eRowA, float* __restrict__ eColA,
    float* __restrict__ eRowB, float* __restrict__ eColB)
{
  __shared__ float fs[64][132];    // feature tile, padded
  __shared__ float WsT[32][132];   // W_h transposed [k][d], padded
  __shared__ float qt[32][65];     // q tile transposed [k][u]
  __shared__ float aAs[32], aBs[32];

  const int bid = blockIdx.x;
  const int tid = threadIdx.x;

  int b, rt, R, h;
  const float *feat, *W;
  _Float16* vt;
  float *eA, *eB;
  int aAoff, aBoff;
  const float *avA, *avB;
  if (bid < 512) {                       // users: 8b x 16rt x 4h
    h = bid & 3; int t2 = bid >> 2; b = t2 >> 4; rt = t2 & 15; R = U_;
    feat = uf; W = Wu; vt = vtB;
    eA = eRowA; eB = eColB;
    avA = a_un; aAoff = 0;  avB = a_nu; aBoff = HD;
  } else {                               // news: 8b x 32rt x 4h
    int t3 = bid - 512;
    h = t3 & 3; int t2 = t3 >> 2; b = t2 >> 5; rt = t2 & 31; R = N_;
    feat = nf; W = Wn; vt = vtA;
    eA = eColA; eB = eRowB;
    avA = a_un; aAoff = HD; avB = a_nu; aBoff = 0;
  }
  const int r0 = rt * 64;

  // ---- load phase: feature tile + W_h(transposed) + attention vectors ----
  const float4* feat4 = (const float4*)(feat + ((size_t)b * R + r0) * DIN);
  #pragma unroll
  for (int i = 0; i < 8; ++i) {
    int f4 = tid + 256 * i;              // 0..2047 float4s of the 64x128 tile
    int row = f4 >> 5, c4 = f4 & 31;
    *(float4*)&fs[row][c4 * 4] = feat4[row * 32 + c4];
  }
  {
    const float4* W4 = (const float4*)(W + (size_t)h * DIN * HD);
    #pragma unroll
    for (int i = 0; i < 4; ++i) {
      int f4 = tid + 256 * i;            // 0..1023
      int d = f4 >> 3, kc = f4 & 7;
      float4 v = W4[f4];
      WsT[kc * 4 + 0][d] = v.x;
      WsT[kc * 4 + 1][d] = v.y;
      WsT[kc * 4 + 2][d] = v.z;
      WsT[kc * 4 + 3][d] = v.w;
    }
    if (tid < 32) {
      aAs[tid] = avA[h * 64 + aAoff + tid];
      aBs[tid] = avB[h * 64 + aBoff + tid];
    }
  }
  __syncthreads();

  // ---- compute phase: q = fs x W_h^T  (thread = 2 k-cols x 4 u-rows) ----
  const int kk = tid & 15, uu = tid >> 4;
  {
    float acc0[4] = {0.f, 0.f, 0.f, 0.f}, acc1[4] = {0.f, 0.f, 0.f, 0.f};
    #pragma unroll 8
    for (int d = 0; d < DIN; d += 4) {
      float4 w0 = *(const float4*)&WsT[kk][d];
      float4 w1 = *(const float4*)&WsT[kk + 16][d];
      #pragma unroll
      for (int i = 0; i < 4; ++i) {
        float4 fv = *(const float4*)&fs[uu + 16 * i][d];
        acc0[i] = fmaf(fv.x, w0.x, acc0[i]); acc0[i] = fmaf(fv.y, w0.y, acc0[i]);
        acc0[i] = fmaf(fv.z, w0.z, acc0[i]); acc0[i] = fmaf(fv.w, w0.w, acc0[i]);
        acc1[i] = fmaf(fv.x, w1.x, acc1[i]); acc1[i] = fmaf(fv.y, w1.y, acc1[i]);
        acc1[i] = fmaf(fv.z, w1.z, acc1[i]); acc1[i] = fmaf(fv.w, w1.w, acc1[i]);
      }
    }
    #pragma unroll
    for (int i = 0; i < 4; ++i) {
      qt[kk][uu + 16 * i] = acc0[i];
      qt[kk + 16][uu + 16 * i] = acc1[i];
    }
  }
  __syncthreads();

  // ---- store phase: tiled vt + e scalars ----
  const int u2 = tid & 63, part = tid >> 6;
  {
    // vt store: c = r0+u2 -> tile (r0+u2)>>5, kk=(r0+u2)&31; element [tile][krow][kk]
    size_t vtbase = (size_t)(b * H_ + h) * (R * HD)
                  + (size_t)((r0 >> 5) + (u2 >> 5)) * (HD * 32) + (u2 & 31);
    #pragma unroll
    for (int jj = 0; jj < 8; ++jj) {
      int krow = part * 8 + jj;
      vt[vtbase + krow * 32] = (_Float16)qt[krow][u2];
    }
  }
  if (part < 2) {
    float a_ = 0.f;
    const float* av = (part == 0) ? aAs : aBs;
    #pragma unroll
    for (int k2 = 0; k2 < HD; ++k2)
      a_ = fmaf(qt[k2][u2], av[k2], a_);
    float* e = (part == 0) ? eA : eB;
    e[(size_t)(b * H_ + h) * R + r0 + u2] = a_ * LOG2E;  // pre-scaled by log2(e)
  }
}

// ---------------- phase 2 core: fused masked-softmax-weighted GEMM + epilogue ----------------
// 32 rows per block (2 row-tiles per wave) — halves vt re-read traffic vs 16-row
// blocks and doubles compute per vt load. Wave = head. Adjacency staged once as
// LDS bitmask via __ballot. Per col-tile: 2 mask words + 2 e float4 + 2 half8 vt
// -> 6 MFMAs. Epilogue: accd[q] = den[row] in every lane -> divide+bias+relu.
template<int RR, int CC, int ROFF, int COFF, int PAD64>
__device__ __forceinline__ void p2_core(
    int b, int rt, int wave, int l,
    const int* __restrict__ adj, const _Float16* __restrict__ vt,
    const float* __restrict__ eRow, const float* __restrict__ eCol,
    const float* __restrict__ bias, float* __restrict__ out,
    unsigned long long* maskU)
{
  constexpr int CW64 = CC / 64;          // u64 words per mask row

  // ---- stage 32 x CC adjacency strip as bits (read once, coalesced) ----
  const int* adjBase = adj + (size_t)b * S_ * S_ + (size_t)(ROFF + rt * 32) * S_ + COFF;
  #pragma unroll 4
  for (int i = 0; i < (32 * CW64) / 4; ++i) {
    int f = i * 4 + wave;
    int row = f / CW64, chunk = f % CW64;
    int av = adjBase[(size_t)row * S_ + chunk * 64 + l];
    unsigned long long m = __ballot(av != 0);
    if (l == 0) maskU[row * PAD64 + chunk] = m;
  }
  __syncthreads();

  const int h = wave;
  const int row16 = l & 15;
  const int cg = (l >> 4) << 3;          // per-lane-group K offset within 32-col tile
  const int r0 = rt * 32;
  const float eq0 = eRow[(size_t)(b * H_ + h) * RR + r0 + row16];
  const float eq1 = eRow[(size_t)(b * H_ + h) * RR + r0 + 16 + row16];
  const float* ecolH = eCol + (size_t)(b * H_ + h) * CC;
  const _Float16* vtb = vt + (size_t)(b * H_ + h) * (CC * HD);
  const unsigned int* maskW = (const unsigned int*)maskU;
  const int mrow0 = row16 * (PAD64 * 2);
  const int mrow1 = (row16 + 16) * (PAD64 * 2);

  f32x4 acc00 = {0.f,0.f,0.f,0.f}, acc01 = {0.f,0.f,0.f,0.f}, accd0 = {0.f,0.f,0.f,0.f};
  f32x4 acc10 = {0.f,0.f,0.f,0.f}, acc11 = {0.f,0.f,0.f,0.f}, accd1 = {0.f,0.f,0.f,0.f};
  half8 ones = {(_Float16)1.f, (_Float16)1.f, (_Float16)1.f, (_Float16)1.f,
                (_Float16)1.f, (_Float16)1.f, (_Float16)1.f, (_Float16)1.f};

  #pragma unroll 2
  for (int t = 0; t < CC / 32; ++t) {
    const int cb = t * 32 + cg;
    unsigned int mb0 = maskW[mrow0 + t] >> cg;   // same-word broadcast across groups
    unsigned int mb1 = maskW[mrow1 + t] >> cg;
    float4 e0 = *(const float4*)(ecolH + cb);
    float4 e1 = *(const float4*)(ecolH + cb + 4);
    float ecv[8] = {e0.x, e0.y, e0.z, e0.w, e1.x, e1.y, e1.z, e1.w};
    float wv0[8], wv1[8];
    #pragma unroll
    for (int j = 0; j < 8; ++j) {
      float s0 = eq0 + ecv[j];                // already log2e-scaled
      float s1 = eq1 + ecv[j];
      float ls0 = fmaxf(s0, 0.2f * s0);       // leaky (positive scale commutes)
      float ls1 = fmaxf(s1, 0.2f * s1);
      ls0 = (mb0 & (1u << j)) ? ls0 : -1e9f;  // masked -> exp2 underflows to exact 0
      ls1 = (mb1 & (1u << j)) ? ls1 : -1e9f;
      wv0[j] = exp2f(ls0);
      wv1[j] = exp2f(ls1);
    }
    union { fp16x2 h2[4]; half8 h8; } uw0, uw1;
    #pragma unroll
    for (int j = 0; j < 4; ++j) {
      uw0.h2[j] = __builtin_amdgcn_cvt_pkrtz(wv0[2 * j], wv0[2 * j + 1]);
      uw1.h2[j] = __builtin_amdgcn_cvt_pkrtz(wv1[2 * j], wv1[2 * j + 1]);
    }
    half8 w0 = uw0.h8, w1 = uw1.h8;
    // tile-interleaved V: [t][hd][kk] -> wave reads 2x1KB contiguous; shared by both row-tiles
    const half8 vf0 = *(const half8*)(vtb + t * (HD * 32) + row16 * 32 + cg);
    const half8 vf1 = *(const half8*)(vtb + t * (HD * 32) + (row16 + 16) * 32 + cg);
    acc00 = __builtin_amdgcn_mfma_f32_16x16x32_f16(w0, vf0, acc00, 0, 0, 0);
    acc01 = __builtin_amdgcn_mfma_f32_16x16x32_f16(w0, vf1, acc01, 0, 0, 0);
    accd0 = __builtin_amdgcn_mfma_f32_16x16x32_f16(w0, ones, accd0, 0, 0, 0);
    acc10 = __builtin_amdgcn_mfma_f32_16x16x32_f16(w1, vf0, acc10, 0, 0, 0);
    acc11 = __builtin_amdgcn_mfma_f32_16x16x32_f16(w1, vf1, acc11, 0, 0, 0);
    accd1 = __builtin_amdgcn_mfma_f32_16x16x32_f16(w1, ones, accd1, 0, 0, 0);
  }

  // ---- fused epilogue: divide, bias, relu, store (both row-tiles) ----
  const int colk = row16;
  const int g4 = (l >> 4) << 2;
  #pragma unroll
  for (int q = 0; q < 4; ++q) {
    int orow = r0 + g4 + q;                  // row-tile 0: C row = (l>>4)*4+q
    size_t o = ((size_t)(b * H_ + h) * RR + orow) * 32 + colk;
    float den = accd0[q];
    float v0 = acc00[q] / den + bias[q * 32 + colk];
    float v1 = acc01[q] / den + bias[q * 32 + colk + 16];
    out[o]      = v0 > 0.f ? v0 : 0.f;
    out[o + 16] = v1 > 0.f ? v1 : 0.f;
  }
  #pragma unroll
  for (int q = 0; q < 4; ++q) {
    int orow = r0 + 16 + g4 + q;             // row-tile 1
    size_t o = ((size_t)(b * H_ + h) * RR + orow) * 32 + colk;
    float den = accd1[q];
    float v0 = acc10[q] / den + bias[q * 32 + colk];
    float v1 = acc11[q] / den + bias[q * 32 + colk + 16];
    out[o]      = v0 > 0.f ? v0 : 0.f;
    out[o + 16] = v1 > 0.f ? v1 : 0.f;
  }
}

// Both directions in ONE grid. XCD-pinned batch decode (b = bid & 7).
__global__ __launch_bounds__(256, 4) void p2_kernel(
    const int* __restrict__ adj,
    const _Float16* __restrict__ vtA, const _Float16* __restrict__ vtB,
    const float* __restrict__ eRowA, const float* __restrict__ eColA,
    const float* __restrict__ eRowB, const float* __restrict__ eColB,
    const float* __restrict__ bu, const float* __restrict__ bn,
    float* __restrict__ out)
{
  __shared__ unsigned long long maskU[32 * 33];   // max of the two instantiations
  const int tid = threadIdx.x;
  const int wave = tid >> 6, l = tid & 63;
  const int bid = blockIdx.x;
  if (bid < B_ * (U_ / 32)) {                     // 256 blocks, rt 0..31
    const int b = bid & 7, rt = bid >> 3;
    p2_core<U_, N_, 0, U_, 33>(b, rt, wave, l, adj, vtA, eRowA, eColA, bu,
                               out, maskU);
  } else {                                        // 512 blocks, rt 0..63
    const int t2 = bid - B_ * (U_ / 32);
    const int b = t2 & 7, rt = t2 >> 3;
    p2_core<N_, U_, U_, 0, 17>(b, rt, wave, l, adj, vtB, eRowB, eColB, bn,
                               out + (size_t)B_ * U_ * 128, maskU);
  }
}

extern "C" void kernel_launch(void* const* d_in, const int* in_sizes, int n_in,
                              void* d_out, int out_size, void* d_ws, size_t ws_size,
                              hipStream_t stream) {
  const float* uf  = (const float*)d_in[0];
  const float* nf  = (const float*)d_in[1];
  const int*   adj = (const int*)d_in[2];
  const float* Wu  = (const float*)d_in[3];
  const float* Wn  = (const float*)d_in[4];
  const float* aun = (const float*)d_in[5];
  const float* anu = (const float*)d_in[6];
  const float* bu  = (const float*)d_in[7];
  const float* bn  = (const float*)d_in[8];

  char* ws = (char*)d_ws;
  size_t off = 0;
  _Float16* vtA = (_Float16*)(ws + off); off += (size_t)B_ * H_ * HD * N_ * 2;  // 4 MB
  _Float16* vtB = (_Float16*)(ws + off); off += (size_t)B_ * H_ * HD * U_ * 2;  // 2 MB
  float* eRowA = (float*)(ws + off); off += (size_t)B_ * H_ * U_ * 4;
  float* eColA = (float*)(ws + off); off += (size_t)B_ * H_ * N_ * 4;
  float* eRowB = (float*)(ws + off); off += (size_t)B_ * H_ * N_ * 4;
  float* eColB = (float*)(ws + off); off += (size_t)B_ * H_ * U_ * 4;
  (void)off; (void)ws_size; (void)in_sizes; (void)n_in; (void)out_size;        // ~7.7 MB total

  p1_kernel<<<512 + 1024, 256, 0, stream>>>(uf, nf, Wu, Wn, aun, anu,
                                            vtA, vtB, eRowA, eColA, eRowB, eColB);
  p2_kernel<<<B_ * (U_ / 32) + B_ * (N_ / 32), 256, 0, stream>>>(
      adj, vtA, vtB, eRowA, eColA, eRowB, eColB, bu, bn, (float*)d_out);
}

// Round 11
// 136.055 us; speedup vs baseline: 1.4576x; 1.1742x over previous
//
#include <hip/hip_runtime.h>
#include <hip/hip_bf16.h>

typedef _Float16 half8 __attribute__((ext_vector_type(8)));
typedef __fp16 fp16x2 __attribute__((ext_vector_type(2)));
typedef float f32x4 __attribute__((ext_vector_type(4)));

#define B_ 8
#define U_ 1024
#define N_ 2048
#define DIN 128
#define H_ 4
#define HD 32
#define S_ 3072
#define LOG2E 1.44269504f

// ---------------- phase 1: projections + e-vectors + tiled f16 V ----------------
// Head-parallel: one block = one (64-row tile, head). Row-side e stored raw
// (log2e-scaled); col-side e stored as (exp2(e), exp2(0.2e)) float2 pairs so p2
// needs NO per-tile transcendentals.
__global__ __launch_bounds__(256) void p1_kernel(
    const float* __restrict__ uf, const float* __restrict__ nf,
    const float* __restrict__ Wu, const float* __restrict__ Wn,
    const float* __restrict__ a_un, const float* __restrict__ a_nu,
    _Float16* __restrict__ vtA, _Float16* __restrict__ vtB,
    float* __restrict__ eRowA, float2* __restrict__ eColA2,
    float* __restrict__ eRowB, float2* __restrict__ eColB2)
{
  __shared__ float fs[64][132];    // feature tile, padded
  __shared__ float WsT[32][132];   // W_h transposed [k][d], padded
  __shared__ float qt[32][65];     // q tile transposed [k][u]
  __shared__ float aAs[32], aBs[32];

  const int bid = blockIdx.x;
  const int tid = threadIdx.x;

  int b, rt, R, h;
  const float *feat, *W;
  _Float16* vt;
  float* eRaw;
  float2* ePair;
  bool part0raw;                         // part0 = a_un-side e; users keep it raw
  int aAoff, aBoff;
  const float *avA, *avB;
  if (bid < 512) {                       // users: 8b x 16rt x 4h
    h = bid & 3; int t2 = bid >> 2; b = t2 >> 4; rt = t2 & 15; R = U_;
    feat = uf; W = Wu; vt = vtB;
    eRaw = eRowA; ePair = eColB2; part0raw = true;
    avA = a_un; aAoff = 0;  avB = a_nu; aBoff = HD;
  } else {                               // news: 8b x 32rt x 4h
    int t3 = bid - 512;
    h = t3 & 3; int t2 = t3 >> 2; b = t2 >> 5; rt = t2 & 31; R = N_;
    feat = nf; W = Wn; vt = vtA;
    eRaw = eRowB; ePair = eColA2; part0raw = false;
    avA = a_un; aAoff = HD; avB = a_nu; aBoff = 0;
  }
  const int r0 = rt * 64;

  // ---- load phase ----
  const float4* feat4 = (const float4*)(feat + ((size_t)b * R + r0) * DIN);
  #pragma unroll
  for (int i = 0; i < 8; ++i) {
    int f4 = tid + 256 * i;
    int row = f4 >> 5, c4 = f4 & 31;
    *(float4*)&fs[row][c4 * 4] = feat4[row * 32 + c4];
  }
  {
    const float4* W4 = (const float4*)(W + (size_t)h * DIN * HD);
    #pragma unroll
    for (int i = 0; i < 4; ++i) {
      int f4 = tid + 256 * i;
      int d = f4 >> 3, kc = f4 & 7;
      float4 v = W4[f4];
      WsT[kc * 4 + 0][d] = v.x;
      WsT[kc * 4 + 1][d] = v.y;
      WsT[kc * 4 + 2][d] = v.z;
      WsT[kc * 4 + 3][d] = v.w;
    }
    if (tid < 32) {
      aAs[tid] = avA[h * 64 + aAoff + tid];
      aBs[tid] = avB[h * 64 + aBoff + tid];
    }
  }
  __syncthreads();

  // ---- compute phase: q = fs x W_h^T ----
  const int kk = tid & 15, uu = tid >> 4;
  {
    float acc0[4] = {0.f, 0.f, 0.f, 0.f}, acc1[4] = {0.f, 0.f, 0.f, 0.f};
    #pragma unroll 8
    for (int d = 0; d < DIN; d += 4) {
      float4 w0 = *(const float4*)&WsT[kk][d];
      float4 w1 = *(const float4*)&WsT[kk + 16][d];
      #pragma unroll
      for (int i = 0; i < 4; ++i) {
        float4 fv = *(const float4*)&fs[uu + 16 * i][d];
        acc0[i] = fmaf(fv.x, w0.x, acc0[i]); acc0[i] = fmaf(fv.y, w0.y, acc0[i]);
        acc0[i] = fmaf(fv.z, w0.z, acc0[i]); acc0[i] = fmaf(fv.w, w0.w, acc0[i]);
        acc1[i] = fmaf(fv.x, w1.x, acc1[i]); acc1[i] = fmaf(fv.y, w1.y, acc1[i]);
        acc1[i] = fmaf(fv.z, w1.z, acc1[i]); acc1[i] = fmaf(fv.w, w1.w, acc1[i]);
      }
    }
    #pragma unroll
    for (int i = 0; i < 4; ++i) {
      qt[kk][uu + 16 * i] = acc0[i];
      qt[kk + 16][uu + 16 * i] = acc1[i];
    }
  }
  __syncthreads();

  // ---- store phase: tiled vt + e ----
  const int u2 = tid & 63, part = tid >> 6;
  {
    size_t vtbase = (size_t)(b * H_ + h) * (R * HD)
                  + (size_t)((r0 >> 5) + (u2 >> 5)) * (HD * 32) + (u2 & 31);
    #pragma unroll
    for (int jj = 0; jj < 8; ++jj) {
      int krow = part * 8 + jj;
      vt[vtbase + krow * 32] = (_Float16)qt[krow][u2];
    }
  }
  if (part < 2) {
    float a_ = 0.f;
    const float* av = (part == 0) ? aAs : aBs;
    #pragma unroll
    for (int k2 = 0; k2 < HD; ++k2)
      a_ = fmaf(qt[k2][u2], av[k2], a_);
    float e = a_ * LOG2E;                // pre-scaled by log2(e)
    size_t idx = (size_t)(b * H_ + h) * R + r0 + u2;
    bool raw = (part == 0) ? part0raw : !part0raw;
    if (raw) eRaw[idx] = e;
    else     ePair[idx] = make_float2(exp2f(e), exp2f(0.2f * e));
  }
}

// ---------------- phase 2: latency-optimized fused masked-softmax GEMM ----------------
struct Tile { float4 e0, e1, e2, e3; half8 v0, v1; unsigned int mb; };

__device__ __forceinline__ Tile load_tile(
    int t, int cg, int row16,
    const float2* __restrict__ ecol2, const _Float16* __restrict__ vtb,
    const unsigned int* maskW, int mrow)
{
  Tile ti;
  const int cb = t * 32 + cg;
  const float4* ep = (const float4*)(ecol2 + cb);   // (E1,E2) pairs, 64B broadcast/group
  ti.e0 = ep[0]; ti.e1 = ep[1]; ti.e2 = ep[2]; ti.e3 = ep[3];
  ti.v0 = *(const half8*)(vtb + t * (HD * 32) + row16 * 32 + cg);
  ti.v1 = *(const half8*)(vtb + t * (HD * 32) + (row16 + 16) * 32 + cg);
  ti.mb = maskW[mrow + t] >> cg;
  return ti;
}

__device__ __forceinline__ void compute_tile(
    const Tile& ti, float F1, float F2, float G, half8 ones,
    f32x4& acc0, f32x4& acc1, f32x4& accd)
{
  // w = mask ? (E1>G ? E1*F1 : E2*F2) : 0   — zero transcendentals in the loop.
  // E1>G <=> exp2(ec)>exp2(-eq) <=> s>0 (monotone); s~0 branches agree (~1).
  float wv[8];
  wv[0] = (ti.mb & 1u)   ? (ti.e0.x > G ? ti.e0.x * F1 : ti.e0.y * F2) : 0.f;
  wv[1] = (ti.mb & 2u)   ? (ti.e0.z > G ? ti.e0.z * F1 : ti.e0.w * F2) : 0.f;
  wv[2] = (ti.mb & 4u)   ? (ti.e1.x > G ? ti.e1.x * F1 : ti.e1.y * F2) : 0.f;
  wv[3] = (ti.mb & 8u)   ? (ti.e1.z > G ? ti.e1.z * F1 : ti.e1.w * F2) : 0.f;
  wv[4] = (ti.mb & 16u)  ? (ti.e2.x > G ? ti.e2.x * F1 : ti.e2.y * F2) : 0.f;
  wv[5] = (ti.mb & 32u)  ? (ti.e2.z > G ? ti.e2.z * F1 : ti.e2.w * F2) : 0.f;
  wv[6] = (ti.mb & 64u)  ? (ti.e3.x > G ? ti.e3.x * F1 : ti.e3.y * F2) : 0.f;
  wv[7] = (ti.mb & 128u) ? (ti.e3.z > G ? ti.e3.z * F1 : ti.e3.w * F2) : 0.f;
  union { fp16x2 h2[4]; half8 h8; } uw;
  uw.h2[0] = __builtin_amdgcn_cvt_pkrtz(wv[0], wv[1]);
  uw.h2[1] = __builtin_amdgcn_cvt_pkrtz(wv[2], wv[3]);
  uw.h2[2] = __builtin_amdgcn_cvt_pkrtz(wv[4], wv[5]);
  uw.h2[3] = __builtin_amdgcn_cvt_pkrtz(wv[6], wv[7]);
  half8 w = uw.h8;
  acc0 = __builtin_amdgcn_mfma_f32_16x16x32_f16(w, ti.v0, acc0, 0, 0, 0);
  acc1 = __builtin_amdgcn_mfma_f32_16x16x32_f16(w, ti.v1, acc1, 0, 0, 0);
  accd = __builtin_amdgcn_mfma_f32_16x16x32_f16(w, ones, accd, 0, 0, 0);
}

// 16 rows/block (max waves: latency-bound regime, round-10 lesson), wave = head,
// 1-deep software pipeline: prefetch tile t+1 while computing tile t.
template<int RR, int CC, int ROFF, int COFF, int PAD64>
__device__ __forceinline__ void p2_core(
    int b, int rt, int wave, int l,
    const int* __restrict__ adj, const _Float16* __restrict__ vt,
    const float* __restrict__ eRow, const float2* __restrict__ eCol2,
    const float* __restrict__ bias, float* __restrict__ out,
    unsigned long long* maskU)
{
  constexpr int CW64 = CC / 64;

  // ---- stage 16 x CC adjacency strip as bits (read once, coalesced) ----
  const int* adjBase = adj + (size_t)b * S_ * S_ + (size_t)(ROFF + rt * 16) * S_ + COFF;
  #pragma unroll 4
  for (int i = 0; i < (16 * CW64) / 4; ++i) {
    int f = i * 4 + wave;
    int row = f / CW64, chunk = f % CW64;
    int av = adjBase[(size_t)row * S_ + chunk * 64 + l];
    unsigned long long m = __ballot(av != 0);
    if (l == 0) maskU[row * PAD64 + chunk] = m;
  }
  __syncthreads();

  const int h = wave;
  const int row16 = l & 15;
  const int cg = (l >> 4) << 3;
  const int r = rt * 16 + row16;
  const float eq = eRow[(size_t)(b * H_ + h) * RR + r];
  const float F1 = exp2f(eq), F2 = exp2f(0.2f * eq), G = exp2f(-eq);
  const float2* ecol2 = eCol2 + (size_t)(b * H_ + h) * CC;
  const _Float16* vtb = vt + (size_t)(b * H_ + h) * (CC * HD);
  const unsigned int* maskW = (const unsigned int*)maskU;
  const int mrow = row16 * (PAD64 * 2);

  f32x4 acc0 = {0.f,0.f,0.f,0.f}, acc1 = {0.f,0.f,0.f,0.f}, accd = {0.f,0.f,0.f,0.f};
  half8 ones = {(_Float16)1.f, (_Float16)1.f, (_Float16)1.f, (_Float16)1.f,
                (_Float16)1.f, (_Float16)1.f, (_Float16)1.f, (_Float16)1.f};

  constexpr int T = CC / 32;
  Tile cur = load_tile(0, cg, row16, ecol2, vtb, maskW, mrow);
  #pragma unroll 2
  for (int t = 0; t < T - 1; ++t) {
    Tile nxt = load_tile(t + 1, cg, row16, ecol2, vtb, maskW, mrow);
    compute_tile(cur, F1, F2, G, ones, acc0, acc1, accd);
    cur = nxt;
  }
  compute_tile(cur, F1, F2, G, ones, acc0, acc1, accd);

  // ---- fused epilogue: divide, bias, relu, store ----
  const int colk = row16;
  const int rowbase = rt * 16 + ((l >> 4) << 2);
  #pragma unroll
  for (int q = 0; q < 4; ++q) {
    int orow = rowbase + q;
    size_t o = ((size_t)(b * H_ + h) * RR + orow) * 32 + colk;
    float den = accd[q];
    float v0 = acc0[q] / den + bias[q * 32 + colk];
    float v1 = acc1[q] / den + bias[q * 32 + colk + 16];
    out[o]      = v0 > 0.f ? v0 : 0.f;
    out[o + 16] = v1 > 0.f ? v1 : 0.f;
  }
}

// Both directions, one grid, XCD-pinned batch decode (b = bid & 7).
__global__ __launch_bounds__(256, 4) void p2_kernel(
    const int* __restrict__ adj,
    const _Float16* __restrict__ vtA, const _Float16* __restrict__ vtB,
    const float* __restrict__ eRowA, const float2* __restrict__ eColA2,
    const float* __restrict__ eRowB, const float2* __restrict__ eColB2,
    const float* __restrict__ bu, const float* __restrict__ bn,
    float* __restrict__ out)
{
  __shared__ unsigned long long maskU[16 * 33];
  const int tid = threadIdx.x;
  const int wave = tid >> 6, l = tid & 63;
  const int bid = blockIdx.x;
  if (bid < B_ * (U_ / 16)) {                     // 512 blocks, rt 0..63
    const int b = bid & 7, rt = bid >> 3;
    p2_core<U_, N_, 0, U_, 33>(b, rt, wave, l, adj, vtA, eRowA, eColA2, bu,
                               out, maskU);
  } else {                                        // 1024 blocks, rt 0..127
    const int t2 = bid - B_ * (U_ / 16);
    const int b = t2 & 7, rt = t2 >> 3;
    p2_core<N_, U_, U_, 0, 17>(b, rt, wave, l, adj, vtB, eRowB, eColB2, bn,
                               out + (size_t)B_ * U_ * 128, maskU);
  }
}

extern "C" void kernel_launch(void* const* d_in, const int* in_sizes, int n_in,
                              void* d_out, int out_size, void* d_ws, size_t ws_size,
                              hipStream_t stream) {
  const float* uf  = (const float*)d_in[0];
  const float* nf  = (const float*)d_in[1];
  const int*   adj = (const int*)d_in[2];
  const float* Wu  = (const float*)d_in[3];
  const float* Wn  = (const float*)d_in[4];
  const float* aun = (const float*)d_in[5];
  const float* anu = (const float*)d_in[6];
  const float* bu  = (const float*)d_in[7];
  const float* bn  = (const float*)d_in[8];

  char* ws = (char*)d_ws;
  size_t off = 0;
  _Float16* vtA = (_Float16*)(ws + off); off += (size_t)B_ * H_ * HD * N_ * 2;  // 4 MB
  _Float16* vtB = (_Float16*)(ws + off); off += (size_t)B_ * H_ * HD * U_ * 2;  // 2 MB
  float*  eRowA  = (float*)(ws + off);  off += (size_t)B_ * H_ * U_ * 4;
  float2* eColA2 = (float2*)(ws + off); off += (size_t)B_ * H_ * N_ * 8;
  float*  eRowB  = (float*)(ws + off);  off += (size_t)B_ * H_ * N_ * 4;
  float2* eColB2 = (float2*)(ws + off); off += (size_t)B_ * H_ * U_ * 8;
  (void)off; (void)ws_size; (void)in_sizes; (void)n_in; (void)out_size;        // ~8.2 MB total

  p1_kernel<<<512 + 1024, 256, 0, stream>>>(uf, nf, Wu, Wn, aun, anu,
                                            vtA, vtB, eRowA, eColA2, eRowB, eColB2);
  p2_kernel<<<B_ * (U_ / 16) + B_ * (N_ / 16), 256, 0, stream>>>(
      adj, vtA, vtB, eRowA, eColA2, eRowB, eColB2, bu, bn, (float*)d_out);
}